// Round 3
// baseline (311.379 us; speedup 1.0000x reference)
//
#include <hip/hip_runtime.h>

#define DEV __device__ __forceinline__

typedef __bf16 bf16;
typedef bf16 bf16x4 __attribute__((ext_vector_type(4)));
typedef bf16 bf16x8 __attribute__((ext_vector_type(8)));
typedef float f32x4 __attribute__((ext_vector_type(4)));

DEV f32x4 mfma16(bf16x8 a, bf16x8 b, f32x4 c) {
  return __builtin_amdgcn_mfma_f32_16x16x32_bf16(a, b, c, 0, 0, 0);
}

DEV void gload_lds16(const bf16* g, bf16* l) {
  __builtin_amdgcn_global_load_lds((const __attribute__((address_space(1))) void*)g,
                                   (__attribute__((address_space(3))) void*)l, 16, 0, 0);
}

// ---------------- LayerNorm (both param sets, shared mean/var) ----------------
__global__ __launch_bounds__(256) void ln_dual(
    const float* __restrict__ x,
    const float* __restrict__ w1, const float* __restrict__ b1,
    const float* __restrict__ w2, const float* __restrict__ b2,
    bf16* __restrict__ h1, bf16* __restrict__ h2)
{
  __shared__ float red[2][4];
  const int row = blockIdx.x, t = threadIdx.x;
  const int lane = t & 63, wave = t >> 6;
  const float4 v = ((const float4*)(x + (size_t)row * 1024))[t];
  float vv[4] = {v.x, v.y, v.z, v.w};
  float s = vv[0] + vv[1] + vv[2] + vv[3];
  float q = vv[0]*vv[0] + vv[1]*vv[1] + vv[2]*vv[2] + vv[3]*vv[3];
  #pragma unroll
  for (int o = 32; o; o >>= 1) { s += __shfl_xor(s, o); q += __shfl_xor(q, o); }
  if (lane == 0) { red[0][wave] = s; red[1][wave] = q; }
  __syncthreads();
  s = red[0][0] + red[0][1] + red[0][2] + red[0][3];
  q = red[1][0] + red[1][1] + red[1][2] + red[1][3];
  const float mu = s * (1.0f / 1024.0f);
  const float var = q * (1.0f / 1024.0f) - mu * mu;
  const float rs = rsqrtf(var + 1e-5f);
  bf16x4 o1, o2;
  #pragma unroll
  for (int j = 0; j < 4; ++j) {
    const int i = t * 4 + j;
    const float xh = (vv[j] - mu) * rs;
    o1[j] = (bf16)(xh * w1[i] + b1[i]);
    o2[j] = (bf16)(xh * w2[i] + b2[i]);
  }
  *(bf16x4*)&h1[(size_t)row * 1024 + t * 4] = o1;
  *(bf16x4*)&h2[(size_t)row * 1024 + t * 4] = o2;
}

// ---------------- f32 -> bf16 cast ----------------
__global__ __launch_bounds__(256) void cast_f32_bf16(
    const float* __restrict__ src, bf16* __restrict__ dst, int n4)
{
  const int i = blockIdx.x * 256 + threadIdx.x;
  if (i >= n4) return;
  const float4 v = ((const float4*)src)[i];
  bf16x4 o = {(bf16)v.x, (bf16)v.y, (bf16)v.z, (bf16)v.w};
  ((bf16x4*)dst)[i] = o;
}

// ---------------- GEMM: C[M,N] = A[M,K] * B[N,K]^T  (both row-major, K contig)
// 128x128 tile, BK=32, 256 threads = 4 waves (2x2), 4x4 16x16x32 frags/wave.
// v2: T3 double-buffered LDS with counted vmcnt(4) (loads stay in flight across
// the barrier), 1D grid with bijective XCD swizzle (T1).
constexpr int EPI_BF16_BIAS = 0;  // bf16 out = acc + bias[n]
constexpr int EPI_GELU      = 1;  // bf16 out = gelu(acc + bias[n])
constexpr int EPI_F32_BIAS  = 2;  // f32 out  = acc + bias[n]
constexpr int EPI_FINAL     = 3;  // f32 out  = acc + bias[n] + add1 + add2

template <int EPI>
__global__ __launch_bounds__(256) void gemm_bt(
    const bf16* __restrict__ A, const bf16* __restrict__ B,
    const float* __restrict__ bias, const float* __restrict__ add1,
    const float* __restrict__ add2, void* __restrict__ Cv,
    int M, int N, int K, int nbx)
{
  __shared__ __align__(16) bf16 As[2][128][32];
  __shared__ __align__(16) bf16 Bs[2][128][32];
  const int tid = threadIdx.x;
  const int lane = tid & 63, wave = tid >> 6;
  const int wm = wave >> 1, wn = wave & 1;
  // XCD-aware swizzle: consecutive swz on one XCD -> same A-panel in its L2
  const int cpx = gridDim.x >> 3;
  const int bid = blockIdx.x;
  const int swz = (bid & 7) * cpx + (bid >> 3);
  const int bm = (swz / nbx) * 128, bn = (swz % nbx) * 128;
  const int g = lane >> 4, c = lane & 15;

  f32x4 acc[4][4] = {};

  const bf16* aS0 = A + (size_t)(bm + wave * 16 + (lane >> 2)) * K + (lane & 3) * 8;
  const bf16* bS0 = B + (size_t)(bn + wave * 16 + (lane >> 2)) * K + (lane & 3) * 8;
  const size_t step64 = (size_t)64 * K;
  const int lo = wave * 16;  // this wave's staging slab (16 rows per 64-row half)

  const int nk = K >> 5;
  // prologue: stage K-tile 0 into buffer 0 (4 loads in flight)
  gload_lds16(aS0, &As[0][lo][0]);
  gload_lds16(aS0 + step64, &As[0][64 + lo][0]);
  gload_lds16(bS0, &Bs[0][lo][0]);
  gload_lds16(bS0 + step64, &Bs[0][64 + lo][0]);

  for (int kt = 0; kt < nk; ++kt) {
    const int cur = kt & 1;
    __builtin_amdgcn_s_barrier();  // all waves done READING buf[cur^1]
    if (kt + 1 < nk) {
      const bf16* ap = aS0 + (kt + 1) * 32;
      const bf16* bp = bS0 + (kt + 1) * 32;
      bf16* aL = &As[cur ^ 1][lo][0];
      bf16* bL = &Bs[cur ^ 1][lo][0];
      gload_lds16(ap, aL);
      gload_lds16(ap + step64, aL + 64 * 32);
      gload_lds16(bp, bL);
      gload_lds16(bp + step64, bL + 64 * 32);
      asm volatile("s_waitcnt vmcnt(4)" ::: "memory");  // old 4 landed; new 4 fly
    } else {
      asm volatile("s_waitcnt vmcnt(0)" ::: "memory");
    }
    __builtin_amdgcn_s_barrier();  // buf[cur] staged by ALL waves
    bf16x8 af[4], bfr[4];
    #pragma unroll
    for (int i = 0; i < 4; ++i) {
      af[i]  = *(const bf16x8*)&As[cur][wm * 64 + i * 16 + c][g * 8];
      bfr[i] = *(const bf16x8*)&Bs[cur][wn * 64 + i * 16 + c][g * 8];
    }
    #pragma unroll
    for (int i = 0; i < 4; ++i)
      #pragma unroll
      for (int j = 0; j < 4; ++j)
        acc[i][j] = mfma16(af[i], bfr[j], acc[i][j]);
  }

  const int row0 = bm + wm * 64 + 4 * g;
  const int col0 = bn + wn * 64 + c;
  #pragma unroll
  for (int i = 0; i < 4; ++i) {
    #pragma unroll
    for (int j = 0; j < 4; ++j) {
      const int cc = col0 + j * 16;
      const float bv = bias[cc];
      #pragma unroll
      for (int r = 0; r < 4; ++r) {
        const int rr = row0 + i * 16 + r;
        const size_t idx = (size_t)rr * N + cc;
        float vo = acc[i][j][r] + bv;
        if constexpr (EPI == EPI_BF16_BIAS) {
          ((bf16*)Cv)[idx] = (bf16)vo;
        } else if constexpr (EPI == EPI_GELU) {
          const float gl = 0.5f * vo * (1.0f + erff(vo * 0.70710678118f));
          ((bf16*)Cv)[idx] = (bf16)gl;
        } else if constexpr (EPI == EPI_F32_BIAS) {
          ((float*)Cv)[idx] = vo;
        } else {
          ((float*)Cv)[idx] = vo + add1[idx] + add2[idx];
        }
      }
    }
  }
}

// ---------------- RoPE + head reshape; also writes V^T ----------------
// qkv [4096][3072] bf16 -> Q,K [B*H][S][64] (rope'd), VT [B*H][64][S]
__global__ __launch_bounds__(256) void rope_reshape(
    const bf16* __restrict__ qkv, const float* __restrict__ freqs,
    bf16* __restrict__ Q, bf16* __restrict__ K, bf16* __restrict__ VT)
{
  __shared__ bf16 vt[64][72];
  const int t = threadIdx.x;
  const int bh = blockIdx.y, b = bh >> 4, h = bh & 15;
  const int sc = blockIdx.x * 64;
  const int sl = t >> 2, s = sc + sl;
  const int d0 = (t & 3) * 16;

  const size_t rowbase = (size_t)(b * 2048 + s) * 3072 + h * 64 + d0;
  const size_t obase = ((size_t)bh * 2048 + s) * 64 + d0;

  #pragma unroll
  for (int which = 0; which < 2; ++which) {
    const bf16* src = qkv + rowbase + which * 1024;
    bf16x8 v0 = *(const bf16x8*)src;
    bf16x8 v1 = *(const bf16x8*)(src + 8);
    if (d0 == 0) {  // dims 0..15 get RoPE: x1=dims0..7, x2=dims8..15
      bf16x8 r0, r1;
      #pragma unroll
      for (int j = 0; j < 8; ++j) {
        const float cs = freqs[s * 16 + j * 2];
        const float sn = freqs[s * 16 + j * 2 + 1];
        const float x1 = (float)v0[j], x2 = (float)v1[j];
        r0[j] = (bf16)(x1 * cs - x2 * sn);
        r1[j] = (bf16)(x1 * sn + x2 * cs);
      }
      v0 = r0; v1 = r1;
    }
    bf16* dst = (which == 0 ? Q : K) + obase;
    *(bf16x8*)dst = v0;
    *(bf16x8*)(dst + 8) = v1;
  }
  {
    const bf16* src = qkv + rowbase + 2048;
    bf16x8 v0 = *(const bf16x8*)src;
    bf16x8 v1 = *(const bf16x8*)(src + 8);
    #pragma unroll
    for (int j = 0; j < 8; ++j) { vt[sl][d0 + j] = v0[j]; vt[sl][d0 + 8 + j] = v1[j]; }
  }
  __syncthreads();
  {
    const int d = t >> 2;
    const int s0 = (t & 3) * 16;
    bf16x8 o0, o1;
    #pragma unroll
    for (int j = 0; j < 8; ++j) { o0[j] = vt[s0 + j][d]; o1[j] = vt[s0 + 8 + j][d]; }
    bf16* dst = VT + ((size_t)bh * 64 + d) * 2048 + sc + s0;
    *(bf16x8*)dst = o0;
    *(bf16x8*)(dst + 8) = o1;
  }
}

// ---------------- Causal flash attention (v2) ----------------
// Q,K: [B*H][S][64], VT: [B*H][64][S], O: [B][S][H*64] bf16.
// 512 threads = 8 waves; each wave owns 16 q rows. QBLK=128, KVBLK=64.
// Double-buffered K/V staging via global_load_lds with pre-swizzled source
// (XOR chunk swizzle ^(row&7) on 16B chunks of 128B rows) so all ds_reads are
// bank-conflict-free. Raw s_barrier + manual vmcnt so next-tile loads overlap
// current-tile compute (T3 minimum 2-phase).
// Scores computed transposed: st = mfma(K, Q) -> C col = q (lane&15).
__global__ __launch_bounds__(512, 4) void attn_kernel(
    const bf16* __restrict__ Q, const bf16* __restrict__ Kg,
    const bf16* __restrict__ VTg, bf16* __restrict__ O)
{
  __shared__ __align__(16) bf16 Ks[2][64][64];
  __shared__ __align__(16) bf16 Vs[2][64][64];
  __shared__ __align__(16) bf16 Ps[8][16][64];

  const int tid = threadIdx.x;
  const int lane = tid & 63, wave = tid >> 6;
  const int g = lane >> 4, c = lane & 15;
  const int bh = blockIdx.y;
  const int qtile = gridDim.x - 1 - blockIdx.x;  // heavy tiles dispatch first
  const int qw = qtile * 128 + wave * 16;

  const bf16* Qp = Q + (size_t)bh * 2048 * 64;
  const bf16* Kp = Kg + (size_t)bh * 2048 * 64;
  const bf16* Vp = VTg + (size_t)bh * 64 * 2048;

  // staging geometry: wave w stages rows w*8..w*8+7; lane -> (row, chunk)
  const int srow = lane >> 3;                 // row within 8-row slab
  const int schunk = (lane & 7) ^ srow;       // pre-swizzled source chunk
  const int svr = wave * 8 + srow;            // absolute LDS row
  bf16* kdst = &Ks[0][wave * 8][0];
  bf16* vdst = &Vs[0][wave * 8][0];
  const size_t kdelta = (size_t)64 * 64;      // Ks[1]-Ks[0] elements

  // Q fragments in registers (B operand: n=q, k=d)
  bf16x8 qreg[2];
  qreg[0] = *(const bf16x8*)&Qp[(size_t)(qw + c) * 64 + g * 8];
  qreg[1] = *(const bf16x8*)&Qp[(size_t)(qw + c) * 64 + 32 + g * 8];

  f32x4 oacc[4] = {};
  float m_ = -1e30f, l_ = 0.0f;
  const int cq = c & 7;

  const int nkb = 2 * qtile + 2;
  // prologue: stage tile 0
  gload_lds16(&Kp[(size_t)(svr) * 64 + schunk * 8], kdst);
  gload_lds16(&Vp[(size_t)(svr) * 2048 + schunk * 8], vdst);
  asm volatile("s_waitcnt vmcnt(0)" ::: "memory");
  __builtin_amdgcn_s_barrier();

  for (int kb = 0; kb < nkb; ++kb) {
    const int cur = kb & 1;
    const int kbase = kb * 64;
    if (kb + 1 < nkb) {  // issue next-tile loads; they fly during compute
      const int nb = kbase + 64;
      gload_lds16(&Kp[(size_t)(nb + svr) * 64 + schunk * 8], kdst + (cur ^ 1) * kdelta);
      gload_lds16(&Vp[(size_t)(svr) * 2048 + nb + schunk * 8], vdst + (cur ^ 1) * kdelta);
    }
    if (kbase <= qw + 15) {  // wave has at least one unmasked key
      // --- QK^T (transposed): st[kf] rows=key 4g+r, col=q c ---
      f32x4 st[4] = {};
      #pragma unroll
      for (int kf = 0; kf < 4; ++kf) {
        #pragma unroll
        for (int kk = 0; kk < 2; ++kk) {
          bf16x8 a = *(const bf16x8*)&Ks[cur][kf * 16 + c][((kk * 4 + g) ^ cq) * 8];
          st[kf] = mfma16(a, qreg[kk], st[kf]);
        }
      }
      // --- online softmax (16 keys/lane over kf,r; reduce over g) ---
      const int q = qw + c;
      const bool need_mask = (kbase + 63 > qw);
      float v[16];
      float tmax = -1e30f;
      #pragma unroll
      for (int kf = 0; kf < 4; ++kf)
        #pragma unroll
        for (int r = 0; r < 4; ++r) {
          float sv = st[kf][r] * 0.125f;
          if (need_mask) {
            const int key = kbase + kf * 16 + 4 * g + r;
            sv = (key <= q) ? sv : -1e30f;
          }
          v[kf * 4 + r] = sv;
          tmax = fmaxf(tmax, sv);
        }
      tmax = fmaxf(tmax, __shfl_xor(tmax, 16));
      tmax = fmaxf(tmax, __shfl_xor(tmax, 32));
      const float mn = fmaxf(m_, tmax);
      const float alpha = __expf(m_ - mn);
      float ts = 0.0f;
      bf16 p[16];
      #pragma unroll
      for (int i = 0; i < 16; ++i) {
        const float pv = __expf(v[i] - mn);
        ts += pv;
        p[i] = (bf16)pv;
      }
      ts += __shfl_xor(ts, 16);
      ts += __shfl_xor(ts, 32);
      l_ = l_ * alpha + ts;
      m_ = mn;
      #pragma unroll
      for (int df = 0; df < 4; ++df) {
        oacc[df][0] *= alpha; oacc[df][1] *= alpha;
        oacc[df][2] *= alpha; oacc[df][3] *= alpha;
      }
      // --- P -> LDS (swizzled), re-read as B fragments ---
      #pragma unroll
      for (int kf = 0; kf < 4; ++kf) {
        bf16x4 pw = {p[kf * 4], p[kf * 4 + 1], p[kf * 4 + 2], p[kf * 4 + 3]};
        *(bf16x4*)&Ps[wave][c][(((kf * 2 + (g >> 1)) ^ cq) * 8) + (g & 1) * 4] = pw;
      }
      bf16x8 pfrag[2];
      #pragma unroll
      for (int kk = 0; kk < 2; ++kk)
        pfrag[kk] = *(const bf16x8*)&Ps[wave][c][((kk * 4 + g) ^ cq) * 8];
      // --- PV: O^T[d][q] += V^T x P ---
      #pragma unroll
      for (int df = 0; df < 4; ++df) {
        #pragma unroll
        for (int kk = 0; kk < 2; ++kk) {
          bf16x8 a = *(const bf16x8*)&Vs[cur][df * 16 + c][((kk * 4 + g) ^ cq) * 8];
          oacc[df] = mfma16(a, pfrag[kk], oacc[df]);
        }
      }
    }
    asm volatile("s_waitcnt vmcnt(0)" ::: "memory");
    __builtin_amdgcn_s_barrier();
  }

  const int b = bh >> 4, h = bh & 15;
  const float inv = 1.0f / l_;
  const int s = qw + c;
  #pragma unroll
  for (int df = 0; df < 4; ++df) {
    bf16x4 o;
    #pragma unroll
    for (int r = 0; r < 4; ++r) o[r] = (bf16)(oacc[df][r] * inv);
    *(bf16x4*)&O[((size_t)(b * 2048 + s)) * 1024 + h * 64 + df * 16 + 4 * g] = o;
  }
}

// ---------------- host orchestration ----------------
extern "C" void kernel_launch(void* const* d_in, const int* in_sizes, int n_in,
                              void* d_out, int out_size, void* d_ws, size_t ws_size,
                              hipStream_t stream) {
  const float* x     = (const float*)d_in[0];
  // d_in[1] attention_mask: causal tril, handled analytically
  const float* W_qkv = (const float*)d_in[2];
  const float* b_qkv = (const float*)d_in[3];
  const float* W_o   = (const float*)d_in[4];
  const float* b_o   = (const float*)d_in[5];
  const float* ln1w  = (const float*)d_in[6];
  const float* ln1b  = (const float*)d_in[7];
  const float* ln2w  = (const float*)d_in[8];
  const float* ln2b  = (const float*)d_in[9];
  const float* W1    = (const float*)d_in[10];
  const float* b1    = (const float*)d_in[11];
  const float* W2    = (const float*)d_in[12];
  const float* b2    = (const float*)d_in[13];
  const float* freqs = (const float*)d_in[14];
  float* out = (float*)d_out;

  char* ws = (char*)d_ws;
  const size_t MB = (size_t)1 << 20;
  bf16* h1  = (bf16*)(ws + 0 * MB);    // 8 MB
  bf16* h2  = (bf16*)(ws + 8 * MB);    // 8 MB
  bf16* wA  = (bf16*)(ws + 16 * MB);   // 8 MB (W_qkv, then W1)
  bf16* wB  = (bf16*)(ws + 24 * MB);   // 8 MB (W_o, then W2)
  bf16* qkv = (bf16*)(ws + 32 * MB);   // 24 MB; region reused by G (32 MB)
  bf16* Qb  = (bf16*)(ws + 64 * MB);   // 8 MB
  bf16* Kb  = (bf16*)(ws + 72 * MB);   // 8 MB
  bf16* VTb = (bf16*)(ws + 80 * MB);   // 8 MB
  bf16* Ob  = (bf16*)(ws + 88 * MB);   // 8 MB
  float* att = (float*)(ws + 64 * MB); // 16 MB f32, reuses Qb/Kb after attn
  bf16* G = qkv;

  ln_dual<<<4096, 256, 0, stream>>>(x, ln1w, ln1b, ln2w, ln2b, h1, h2);
  cast_f32_bf16<<<3072, 256, 0, stream>>>(W_qkv, wA, 786432);
  gemm_bt<EPI_BF16_BIAS><<<768, 256, 0, stream>>>(
      h1, wA, b_qkv, nullptr, nullptr, qkv, 4096, 3072, 1024, 24);
  rope_reshape<<<dim3(32, 32), 256, 0, stream>>>(qkv, freqs, Qb, Kb, VTb);
  attn_kernel<<<dim3(16, 32), 512, 0, stream>>>(Qb, Kb, VTb, Ob);
  cast_f32_bf16<<<1024, 256, 0, stream>>>(W_o, wB, 262144);
  gemm_bt<EPI_F32_BIAS><<<256, 256, 0, stream>>>(
      Ob, wB, b_o, nullptr, nullptr, att, 4096, 1024, 1024, 8);
  cast_f32_bf16<<<4096, 256, 0, stream>>>(W1, wA, 1048576);
  gemm_bt<EPI_GELU><<<1024, 256, 0, stream>>>(
      h2, wA, b1, nullptr, nullptr, G, 4096, 4096, 1024, 32);
  cast_f32_bf16<<<4096, 256, 0, stream>>>(W2, wB, 1048576);
  gemm_bt<EPI_FINAL><<<256, 256, 0, stream>>>(
      G, wB, b2, x, att, out, 4096, 1024, 4096, 8);
}

// Round 4
// 259.322 us; speedup vs baseline: 1.2007x; 1.2007x over previous
//
#include <hip/hip_runtime.h>

#define DEV __device__ __forceinline__

typedef __bf16 bf16;
typedef bf16 bf16x4 __attribute__((ext_vector_type(4)));
typedef bf16 bf16x8 __attribute__((ext_vector_type(8)));
typedef float f32x4 __attribute__((ext_vector_type(4)));

DEV f32x4 mfma16(bf16x8 a, bf16x8 b, f32x4 c) {
  return __builtin_amdgcn_mfma_f32_16x16x32_bf16(a, b, c, 0, 0, 0);
}

DEV void gload_lds16(const bf16* g, bf16* l) {
  __builtin_amdgcn_global_load_lds((const __attribute__((address_space(1))) void*)g,
                                   (__attribute__((address_space(3))) void*)l, 16, 0, 0);
}

// vmcnt-counted wait fused with barrier so the compiler can't move memory ops
// between them ("memory" clobber orders ds_read/gload on both sides).
#define WAITBAR(NSTR) asm volatile("s_waitcnt vmcnt(" NSTR ")\n\ts_barrier" ::: "memory")

// ---------------- LayerNorm (both param sets, shared mean/var) ----------------
__global__ __launch_bounds__(256) void ln_dual(
    const float* __restrict__ x,
    const float* __restrict__ w1, const float* __restrict__ b1,
    const float* __restrict__ w2, const float* __restrict__ b2,
    bf16* __restrict__ h1, bf16* __restrict__ h2)
{
  __shared__ float red[2][4];
  const int row = blockIdx.x, t = threadIdx.x;
  const int lane = t & 63, wave = t >> 6;
  const float4 v = ((const float4*)(x + (size_t)row * 1024))[t];
  float vv[4] = {v.x, v.y, v.z, v.w};
  float s = vv[0] + vv[1] + vv[2] + vv[3];
  float q = vv[0]*vv[0] + vv[1]*vv[1] + vv[2]*vv[2] + vv[3]*vv[3];
  #pragma unroll
  for (int o = 32; o; o >>= 1) { s += __shfl_xor(s, o); q += __shfl_xor(q, o); }
  if (lane == 0) { red[0][wave] = s; red[1][wave] = q; }
  __syncthreads();
  s = red[0][0] + red[0][1] + red[0][2] + red[0][3];
  q = red[1][0] + red[1][1] + red[1][2] + red[1][3];
  const float mu = s * (1.0f / 1024.0f);
  const float var = q * (1.0f / 1024.0f) - mu * mu;
  const float rs = rsqrtf(var + 1e-5f);
  bf16x4 o1, o2;
  #pragma unroll
  for (int j = 0; j < 4; ++j) {
    const int i = t * 4 + j;
    const float xh = (vv[j] - mu) * rs;
    o1[j] = (bf16)(xh * w1[i] + b1[i]);
    o2[j] = (bf16)(xh * w2[i] + b2[i]);
  }
  *(bf16x4*)&h1[(size_t)row * 1024 + t * 4] = o1;
  *(bf16x4*)&h2[(size_t)row * 1024 + t * 4] = o2;
}

// ---------------- f32 -> bf16 casts ----------------
__global__ __launch_bounds__(256) void cast_f32_bf16(
    const float* __restrict__ src, bf16* __restrict__ dst, int n4)
{
  const int i = blockIdx.x * 256 + threadIdx.x;
  if (i >= n4) return;
  const float4 v = ((const float4*)src)[i];
  bf16x4 o = {(bf16)v.x, (bf16)v.y, (bf16)v.z, (bf16)v.w};
  ((bf16x4*)dst)[i] = o;
}

// strided cast: one block per row (for packing [W_o | W2] into wCat, ld=5120)
__global__ __launch_bounds__(256) void cast_row(
    const float* __restrict__ src, bf16* __restrict__ dst, int ldd, int C)
{
  const int row = blockIdx.x;
  for (int off = threadIdx.x * 4; off < C; off += 1024) {
    const float4 v = *(const float4*)&src[(size_t)row * C + off];
    bf16x4 o = {(bf16)v.x, (bf16)v.y, (bf16)v.z, (bf16)v.w};
    *(bf16x4*)&dst[(size_t)row * ldd + off] = o;
  }
}

// ---------------- GEMM 256x256xBK64, 8 waves, 4-phase pipelined ----------------
// C[M,N] = A[M,K] x B[N,K]^T, both row stride K. Wave (wm,wn) owns 128x64.
// Per K-tile: 8 staging units of 8KB (1 gload_lds/thread each):
//   A-unit(kkh,ub) = rows {ub*64..}+{128+ub*64..} x cols kkh*32+[0,32)
//   B-unit(kkh,ub) = rows ub*128+[0,128)        x cols kkh*32+[0,32)
// Unit interior: [128 rows][32 cols], 16B chunks XOR-swizzled: ch' = ch^((lr>>1)&3)
// (pre-swizzled global source, swizzled ds_read -> uniform bank spread).
// Issue order per iter: [B0,B1][A0,A1][B2,B3][A2,A3]; uniform vmcnt(6) keeps
// 3 units in flight (landed-set provably covers each phase's reads).
DEV bf16x8 ldfrag(const bf16* unit, int lr, int g) {
  return *(const bf16x8*)&unit[lr * 32 + ((g ^ ((lr >> 1) & 3)) << 3)];
}
DEV void read_bfr(const bf16* unit, int blr, int g, bf16x8 bfr[4]) {
  #pragma unroll
  for (int nj = 0; nj < 4; ++nj) bfr[nj] = ldfrag(unit, blr + nj * 16, g);
}
DEV void read_af(const bf16* unit, int alr, int g, bf16x8 af[4]) {
  #pragma unroll
  for (int ml = 0; ml < 4; ++ml) af[ml] = ldfrag(unit, alr + ml * 16, g);
}
DEV void do_mfma(const bf16x8 af[4], const bf16x8 bfr[4], f32x4 acc[8][4], int mh) {
  __builtin_amdgcn_s_setprio(1);
  #pragma unroll
  for (int ml = 0; ml < 4; ++ml)
    #pragma unroll
    for (int nj = 0; nj < 4; ++nj)
      acc[mh * 4 + ml][nj] = mfma16(af[ml], bfr[nj], acc[mh * 4 + ml][nj]);
  __builtin_amdgcn_s_setprio(0);
}

// EPI: 0 = bf16 + bias; 1 = bf16 gelu(acc+bias); 2 = f32 partial (split-K, no bias)
template <int EPI>
__global__ __launch_bounds__(512, 2) void gemm256(
    const bf16* __restrict__ A, const bf16* __restrict__ B,
    const float* __restrict__ bias, void* __restrict__ Cv,
    float* __restrict__ P1, float* __restrict__ P2, float* __restrict__ P3,
    int K, int ldc, int ntiles, int nbx, int nkt)
{
  __shared__ __align__(16) bf16 As[2][2][2][4096];  // [buf][kkh][ublk][128*32]
  __shared__ __align__(16) bf16 Bs[2][2][2][4096];
  const int tid = threadIdx.x;
  const int lane = tid & 63, wave = tid >> 6;
  const int wm = wave >> 2, wn = wave & 3;
  const int g = lane >> 4, c = lane & 15;
  const int cpx = gridDim.x >> 3;  // grid % 8 == 0 for all our launches
  const int swz = ((int)blockIdx.x & 7) * cpx + ((int)blockIdx.x >> 3);
  const int tile = swz % ntiles;
  const int sk = swz / ntiles;
  const int bm = (tile / nbx) * 256, bn = (tile % nbx) * 256;

  // staging source geometry (pre-swizzled so linear LDS dst == swizzled layout)
  const int slr = tid >> 2;
  const int sch = (tid & 3) ^ ((tid >> 3) & 3);
  const bf16* aU[2][2];
  const bf16* bU[2][2];
  {
    const bf16* a0 = A + (size_t)(bm + ((slr >> 6) * 128) + (slr & 63)) * K
                       + (size_t)sk * nkt * 64 + sch * 8;
    const bf16* b0 = B + (size_t)(bn + slr) * K + (size_t)sk * nkt * 64 + sch * 8;
    aU[0][0] = a0;            aU[0][1] = a0 + (size_t)64 * K;
    aU[1][0] = a0 + 32;       aU[1][1] = a0 + (size_t)64 * K + 32;
    bU[0][0] = b0;            bU[0][1] = b0 + (size_t)128 * K;
    bU[1][0] = b0 + 32;       bU[1][1] = b0 + (size_t)128 * K + 32;
  }
#define STG_A(bf_, kkh_, ub_, ko_) gload_lds16(aU[kkh_][ub_] + (ko_), &As[bf_][kkh_][ub_][wave * 512])
#define STG_B(bf_, kkh_, ub_, ko_) gload_lds16(bU[kkh_][ub_] + (ko_), &Bs[bf_][kkh_][ub_][wave * 512])

  f32x4 acc[8][4] = {};
  bf16x8 bfr[4], af[4];
  const int alr = (wm << 6) + c;        // + ml*16 ; A-unit local row
  const int blr = ((wn & 1) << 6) + c;  // + nj*16 ; B-unit local row
  const int bub = wn >> 1;              // B ublk for this wave

  // prologue: tile 0 in canonical order
  STG_B(0, 0, 0, 0); STG_B(0, 0, 1, 0); STG_A(0, 0, 0, 0); STG_A(0, 0, 1, 0);
  STG_B(0, 1, 0, 0); STG_B(0, 1, 1, 0); STG_A(0, 1, 0, 0); STG_A(0, 1, 1, 0);

  for (int t = 0; t < nkt - 1; ++t) {
    const int buf = t & 1, nxt = buf ^ 1;
    const int ko = (t + 1) * 64;
    // phase 0: kk=0, mh=0
    STG_B(nxt, 0, 0, ko); STG_B(nxt, 0, 1, ko);
    WAITBAR("6");
    read_bfr(&Bs[buf][0][bub][0], blr, g, bfr);
    read_af(&As[buf][0][0][0], alr, g, af);
    do_mfma(af, bfr, acc, 0);
    // phase 1: kk=0, mh=1 (bfr reused)
    STG_A(nxt, 0, 0, ko); STG_A(nxt, 0, 1, ko);
    WAITBAR("6");
    read_af(&As[buf][0][1][0], alr, g, af);
    do_mfma(af, bfr, acc, 1);
    // phase 2: kk=1, mh=0
    STG_B(nxt, 1, 0, ko); STG_B(nxt, 1, 1, ko);
    WAITBAR("6");
    read_bfr(&Bs[buf][1][bub][0], blr, g, bfr);
    read_af(&As[buf][1][0][0], alr, g, af);
    do_mfma(af, bfr, acc, 0);
    // phase 3: kk=1, mh=1
    STG_A(nxt, 1, 0, ko); STG_A(nxt, 1, 1, ko);
    WAITBAR("6");
    read_af(&As[buf][1][1][0], alr, g, af);
    do_mfma(af, bfr, acc, 1);
  }
  {  // final K-tile: drain waits (4 -> 1 -> 0), no issues
    const int buf = (nkt - 1) & 1;
    WAITBAR("4");
    read_bfr(&Bs[buf][0][bub][0], blr, g, bfr);
    read_af(&As[buf][0][0][0], alr, g, af);
    do_mfma(af, bfr, acc, 0);
    read_af(&As[buf][0][1][0], alr, g, af);  // landed with the "4" wait
    do_mfma(af, bfr, acc, 1);
    WAITBAR("1");
    read_bfr(&Bs[buf][1][bub][0], blr, g, bfr);
    read_af(&As[buf][1][0][0], alr, g, af);
    do_mfma(af, bfr, acc, 0);
    WAITBAR("0");
    read_af(&As[buf][1][1][0], alr, g, af);
    do_mfma(af, bfr, acc, 1);
  }
#undef STG_A
#undef STG_B

  float* Pp = nullptr;
  if constexpr (EPI == 2) Pp = (sk == 1) ? P1 : (sk == 2) ? P2 : (sk == 3) ? P3 : (float*)Cv;
  const int row0 = bm + wm * 128 + 4 * g;
  const int col0 = bn + wn * 64 + c;
  #pragma unroll
  for (int mi = 0; mi < 8; ++mi) {
    #pragma unroll
    for (int nj = 0; nj < 4; ++nj) {
      const int col = col0 + nj * 16;
      float bv = 0.0f;
      if constexpr (EPI < 2) bv = bias[col];
      #pragma unroll
      for (int r = 0; r < 4; ++r) {
        const size_t idx = (size_t)(row0 + mi * 16 + r) * ldc + col;
        const float vo = acc[mi][nj][r] + bv;
        if constexpr (EPI == 0) {
          ((bf16*)Cv)[idx] = (bf16)vo;
        } else if constexpr (EPI == 1) {
          ((bf16*)Cv)[idx] = (bf16)(0.5f * vo * (1.0f + erff(vo * 0.70710678118f)));
        } else {
          Pp[idx] = vo;
        }
      }
    }
  }
}

// ---------------- combine: out = p3(=out) + p0 + p1 + p2 + x + b_o + b2 ----------------
__global__ __launch_bounds__(256) void combine_out(
    const float* __restrict__ p0, const float* __restrict__ p1,
    const float* __restrict__ p2, const float* __restrict__ x,
    const float* __restrict__ bo, const float* __restrict__ b2,
    float* __restrict__ out)
{
  const int row = blockIdx.x, t = threadIdx.x;
  const size_t base = (size_t)row * 1024 + t * 4;
  float4 a = *(float4*)&out[base];
  const float4 v0 = *(const float4*)&p0[base];
  const float4 v1 = *(const float4*)&p1[base];
  const float4 v2 = *(const float4*)&p2[base];
  const float4 vx = *(const float4*)&x[base];
  const float4 vb = *(const float4*)&bo[t * 4];
  const float4 vc = *(const float4*)&b2[t * 4];
  a.x += v0.x + v1.x + v2.x + vx.x + vb.x + vc.x;
  a.y += v0.y + v1.y + v2.y + vx.y + vb.y + vc.y;
  a.z += v0.z + v1.z + v2.z + vx.z + vb.z + vc.z;
  a.w += v0.w + v1.w + v2.w + vx.w + vb.w + vc.w;
  *(float4*)&out[base] = a;
}

// ---------------- RoPE + head reshape; also writes V^T ----------------
__global__ __launch_bounds__(256) void rope_reshape(
    const bf16* __restrict__ qkv, const float* __restrict__ freqs,
    bf16* __restrict__ Q, bf16* __restrict__ K, bf16* __restrict__ VT)
{
  __shared__ bf16 vt[64][72];
  const int t = threadIdx.x;
  const int bh = blockIdx.y, b = bh >> 4, h = bh & 15;
  const int sc = blockIdx.x * 64;
  const int sl = t >> 2, s = sc + sl;
  const int d0 = (t & 3) * 16;

  const size_t rowbase = (size_t)(b * 2048 + s) * 3072 + h * 64 + d0;
  const size_t obase = ((size_t)bh * 2048 + s) * 64 + d0;

  #pragma unroll
  for (int which = 0; which < 2; ++which) {
    const bf16* src = qkv + rowbase + which * 1024;
    bf16x8 v0 = *(const bf16x8*)src;
    bf16x8 v1 = *(const bf16x8*)(src + 8);
    if (d0 == 0) {
      bf16x8 r0, r1;
      #pragma unroll
      for (int j = 0; j < 8; ++j) {
        const float cs = freqs[s * 16 + j * 2];
        const float sn = freqs[s * 16 + j * 2 + 1];
        const float x1 = (float)v0[j], x2 = (float)v1[j];
        r0[j] = (bf16)(x1 * cs - x2 * sn);
        r1[j] = (bf16)(x1 * sn + x2 * cs);
      }
      v0 = r0; v1 = r1;
    }
    bf16* dst = (which == 0 ? Q : K) + obase;
    *(bf16x8*)dst = v0;
    *(bf16x8*)(dst + 8) = v1;
  }
  {
    const bf16* src = qkv + rowbase + 2048;
    bf16x8 v0 = *(const bf16x8*)src;
    bf16x8 v1 = *(const bf16x8*)(src + 8);
    #pragma unroll
    for (int j = 0; j < 8; ++j) { vt[sl][d0 + j] = v0[j]; vt[sl][d0 + 8 + j] = v1[j]; }
  }
  __syncthreads();
  {
    const int d = t >> 2;
    const int s0 = (t & 3) * 16;
    bf16x8 o0, o1;
    #pragma unroll
    for (int j = 0; j < 8; ++j) { o0[j] = vt[s0 + j][d]; o1[j] = vt[s0 + 8 + j][d]; }
    bf16* dst = VT + ((size_t)bh * 64 + d) * 2048 + sc + s0;
    *(bf16x8*)dst = o0;
    *(bf16x8*)(dst + 8) = o1;
  }
}

// ---------------- Causal flash attention (O written at stride ldO) ----------------
__global__ __launch_bounds__(512, 4) void attn_kernel(
    const bf16* __restrict__ Q, const bf16* __restrict__ Kg,
    const bf16* __restrict__ VTg, bf16* __restrict__ O, int ldO)
{
  __shared__ __align__(16) bf16 Ks[2][64][64];
  __shared__ __align__(16) bf16 Vs[2][64][64];
  __shared__ __align__(16) bf16 Ps[8][16][64];

  const int tid = threadIdx.x;
  const int lane = tid & 63, wave = tid >> 6;
  const int g = lane >> 4, c = lane & 15;
  const int bh = blockIdx.y;
  const int qtile = gridDim.x - 1 - blockIdx.x;
  const int qw = qtile * 128 + wave * 16;

  const bf16* Qp = Q + (size_t)bh * 2048 * 64;
  const bf16* Kp = Kg + (size_t)bh * 2048 * 64;
  const bf16* Vp = VTg + (size_t)bh * 64 * 2048;

  const int srow = lane >> 3;
  const int schunk = (lane & 7) ^ srow;
  const int svr = wave * 8 + srow;
  bf16* kdst = &Ks[0][wave * 8][0];
  bf16* vdst = &Vs[0][wave * 8][0];
  const size_t kdelta = (size_t)64 * 64;

  bf16x8 qreg[2];
  qreg[0] = *(const bf16x8*)&Qp[(size_t)(qw + c) * 64 + g * 8];
  qreg[1] = *(const bf16x8*)&Qp[(size_t)(qw + c) * 64 + 32 + g * 8];

  f32x4 oacc[4] = {};
  float m_ = -1e30f, l_ = 0.0f;
  const int cq = c & 7;

  const int nkb = 2 * qtile + 2;
  gload_lds16(&Kp[(size_t)(svr) * 64 + schunk * 8], kdst);
  gload_lds16(&Vp[(size_t)(svr) * 2048 + schunk * 8], vdst);
  asm volatile("s_waitcnt vmcnt(0)" ::: "memory");
  __builtin_amdgcn_s_barrier();

  for (int kb = 0; kb < nkb; ++kb) {
    const int cur = kb & 1;
    const int kbase = kb * 64;
    if (kb + 1 < nkb) {
      const int nb = kbase + 64;
      gload_lds16(&Kp[(size_t)(nb + svr) * 64 + schunk * 8], kdst + (cur ^ 1) * kdelta);
      gload_lds16(&Vp[(size_t)(svr) * 2048 + nb + schunk * 8], vdst + (cur ^ 1) * kdelta);
    }
    if (kbase <= qw + 15) {
      f32x4 st[4] = {};
      #pragma unroll
      for (int kf = 0; kf < 4; ++kf) {
        #pragma unroll
        for (int kk = 0; kk < 2; ++kk) {
          bf16x8 a = *(const bf16x8*)&Ks[cur][kf * 16 + c][((kk * 4 + g) ^ cq) * 8];
          st[kf] = mfma16(a, qreg[kk], st[kf]);
        }
      }
      const int q = qw + c;
      const bool need_mask = (kbase + 63 > qw);
      float v[16];
      float tmax = -1e30f;
      #pragma unroll
      for (int kf = 0; kf < 4; ++kf)
        #pragma unroll
        for (int r = 0; r < 4; ++r) {
          float sv = st[kf][r] * 0.125f;
          if (need_mask) {
            const int key = kbase + kf * 16 + 4 * g + r;
            sv = (key <= q) ? sv : -1e30f;
          }
          v[kf * 4 + r] = sv;
          tmax = fmaxf(tmax, sv);
        }
      tmax = fmaxf(tmax, __shfl_xor(tmax, 16));
      tmax = fmaxf(tmax, __shfl_xor(tmax, 32));
      const float mn = fmaxf(m_, tmax);
      const float alpha = __expf(m_ - mn);
      float ts = 0.0f;
      bf16 p[16];
      #pragma unroll
      for (int i = 0; i < 16; ++i) {
        const float pv = __expf(v[i] - mn);
        ts += pv;
        p[i] = (bf16)pv;
      }
      ts += __shfl_xor(ts, 16);
      ts += __shfl_xor(ts, 32);
      l_ = l_ * alpha + ts;
      m_ = mn;
      #pragma unroll
      for (int df = 0; df < 4; ++df) {
        oacc[df][0] *= alpha; oacc[df][1] *= alpha;
        oacc[df][2] *= alpha; oacc[df][3] *= alpha;
      }
      #pragma unroll
      for (int kf = 0; kf < 4; ++kf) {
        bf16x4 pw = {p[kf * 4], p[kf * 4 + 1], p[kf * 4 + 2], p[kf * 4 + 3]};
        *(bf16x4*)&Ps[wave][c][(((kf * 2 + (g >> 1)) ^ cq) * 8) + (g & 1) * 4] = pw;
      }
      bf16x8 pfrag[2];
      #pragma unroll
      for (int kk = 0; kk < 2; ++kk)
        pfrag[kk] = *(const bf16x8*)&Ps[wave][c][((kk * 4 + g) ^ cq) * 8];
      #pragma unroll
      for (int df = 0; df < 4; ++df) {
        #pragma unroll
        for (int kk = 0; kk < 2; ++kk) {
          bf16x8 a = *(const bf16x8*)&Vs[cur][df * 16 + c][((kk * 4 + g) ^ cq) * 8];
          oacc[df] = mfma16(a, pfrag[kk], oacc[df]);
        }
      }
    }
    asm volatile("s_waitcnt vmcnt(0)" ::: "memory");
    __builtin_amdgcn_s_barrier();
  }

  const int b = bh >> 4, h = bh & 15;
  const float inv = 1.0f / l_;
  const int s = qw + c;
  #pragma unroll
  for (int df = 0; df < 4; ++df) {
    bf16x4 o;
    #pragma unroll
    for (int r = 0; r < 4; ++r) o[r] = (bf16)(oacc[df][r] * inv);
    *(bf16x4*)&O[(size_t)(b * 2048 + s) * ldO + h * 64 + df * 16 + 4 * g] = o;
  }
}

// ---------------- host orchestration ----------------
extern "C" void kernel_launch(void* const* d_in, const int* in_sizes, int n_in,
                              void* d_out, int out_size, void* d_ws, size_t ws_size,
                              hipStream_t stream) {
  const float* x     = (const float*)d_in[0];
  const float* W_qkv = (const float*)d_in[2];
  const float* b_qkv = (const float*)d_in[3];
  const float* W_o   = (const float*)d_in[4];
  const float* b_o   = (const float*)d_in[5];
  const float* ln1w  = (const float*)d_in[6];
  const float* ln1b  = (const float*)d_in[7];
  const float* ln2w  = (const float*)d_in[8];
  const float* ln2b  = (const float*)d_in[9];
  const float* W1    = (const float*)d_in[10];
  const float* b1    = (const float*)d_in[11];
  const float* W2    = (const float*)d_in[12];
  const float* b2    = (const float*)d_in[13];
  const float* freqs = (const float*)d_in[14];
  float* out = (float*)d_out;

  char* ws = (char*)d_ws;
  const size_t MB = (size_t)1 << 20;
  // live ranges (MB): h1 0-8, h2 8-16, wQKV 16-22, wCat 22-32, w1 32-40,
  // qkv 40-64, Qb 64-72, Kb 72-80, VTb 80-88, A2 88-128.
  // split-K partials reuse dead regions: p0@0 (h1+h2), p1@40 (qkv), p2@64 (Qb+Kb).
  bf16* h1   = (bf16*)(ws + 0 * MB);
  bf16* h2   = (bf16*)(ws + 8 * MB);
  bf16* wQKV = (bf16*)(ws + 16 * MB);
  bf16* wCat = (bf16*)(ws + 22 * MB);
  bf16* w1   = (bf16*)(ws + 32 * MB);
  bf16* qkv  = (bf16*)(ws + 40 * MB);
  bf16* Qb   = (bf16*)(ws + 64 * MB);
  bf16* Kb   = (bf16*)(ws + 72 * MB);
  bf16* VTb  = (bf16*)(ws + 80 * MB);
  bf16* A2   = (bf16*)(ws + 88 * MB);   // [4096][5120]: cols 0-1023 = Ob, 1024+ = G
  float* p0  = (float*)(ws + 0 * MB);
  float* p1  = (float*)(ws + 40 * MB);
  float* p2  = (float*)(ws + 64 * MB);

  ln_dual<<<4096, 256, 0, stream>>>(x, ln1w, ln1b, ln2w, ln2b, h1, h2);
  cast_f32_bf16<<<3072, 256, 0, stream>>>(W_qkv, wQKV, 786432);
  cast_f32_bf16<<<4096, 256, 0, stream>>>(W1, w1, 1048576);
  cast_row<<<1024, 256, 0, stream>>>(W_o, wCat, 5120, 1024);
  cast_row<<<1024, 256, 0, stream>>>(W2, wCat + 1024, 5120, 4096);

  // QKV: [4096,3072] = h1[4096,1024] x wQKV[3072,1024]^T
  gemm256<0><<<192, 512, 0, stream>>>(h1, wQKV, b_qkv, qkv,
                                      nullptr, nullptr, nullptr,
                                      1024, 3072, 192, 12, 16);
  rope_reshape<<<dim3(32, 32), 256, 0, stream>>>(qkv, freqs, Qb, Kb, VTb);
  attn_kernel<<<dim3(16, 32), 512, 0, stream>>>(Qb, Kb, VTb, A2, 5120);
  // FF1: gelu(h2 x W1^T + b1) -> A2 cols 1024..5119
  gemm256<1><<<256, 512, 0, stream>>>(h2, w1, b1, A2 + 1024,
                                      nullptr, nullptr, nullptr,
                                      1024, 5120, 256, 16, 16);
  // fused Wo+FF2: [4096,1024] = A2[4096,5120] x wCat[1024,5120]^T, split-K4
  gemm256<2><<<256, 512, 0, stream>>>(A2, wCat, nullptr, p0,
                                      p1, p2, out,
                                      5120, 1024, 64, 4, 20);
  combine_out<<<4096, 256, 0, stream>>>(p0, p1, p2, x, b_o, b2, out);
}